// Round 4
// baseline (244.645 us; speedup 1.0000x reference)
//
#include <hip/hip_runtime.h>

// MHA: B=2, S=2048, D=1024, H=16, hd=64. fp32 in/out, bf16 MFMA internally.
// R13 == R12 resubmit (R12 bench was an infra failure, no data).
// R12: attn reverted to R9 structure (no split-K; R10/R11 showed extra waves
// don't help: no pipe saturated, latency-bound at sync points). Change: BK=64
// per iteration (two 32-k halves, NO barrier between them) -> barriers 64->32,
// 2x independent work per sync window; compiler overlaps half1 QK with half0
// PV/repack. Bufs 16KB (K 8K + V 8K), 4 bufs = 64KB LDS, 2 blocks/CU.
// Per iter: 8 mask float4 + 4 DMA -> vmcnt(24) = distance-2. GEMMs unchanged.

typedef __bf16 bf16;
typedef __bf16 bf16x2 __attribute__((ext_vector_type(2)));
typedef __bf16 bf16x4 __attribute__((ext_vector_type(4)));
typedef __bf16 bf16x8 __attribute__((ext_vector_type(8)));
typedef float f32x4 __attribute__((ext_vector_type(4)));

#define MFMA(a, b, c) __builtin_amdgcn_mfma_f32_16x16x32_bf16((a), (b), (c), 0, 0, 0)

#if __has_builtin(__builtin_amdgcn_exp2f)
#define EXP2(x) __builtin_amdgcn_exp2f(x)
#else
#define EXP2(x) exp2f(x)
#endif

__device__ __forceinline__ void load_lds16(const bf16* g, void* l) {
    __builtin_amdgcn_global_load_lds(
        (const __attribute__((address_space(1))) unsigned int*)g,
        (__attribute__((address_space(3))) unsigned int*)l, 16, 0, 0);
}

// ---------------- cast fp32 -> bf16, 4 elems/thread ----------------
__global__ void cast4_kernel(const float* __restrict__ in, bf16* __restrict__ out, int n4) {
    int i = blockIdx.x * blockDim.x + threadIdx.x;
    if (i < n4) {
        float4 v = ((const float4*)in)[i];
        bf16x4 o = {(bf16)v.x, (bf16)v.y, (bf16)v.z, (bf16)v.w};
        ((bf16x4*)out)[i] = o;
    }
}

// ---------------- transpose + cast: in [R,C] fp32 -> out [C,R] bf16 ----------------
__global__ void transpose_cast_kernel(const float* __restrict__ in, bf16* __restrict__ out,
                                      int R, int C) {
    __shared__ float tile[32][33];
    int bx = blockIdx.x * 32;
    int by = blockIdx.y * 32;
    int tx = threadIdx.x, ty = threadIdx.y;  // (32,8)
    for (int i = 0; i < 32; i += 8)
        tile[ty + i][tx] = in[(size_t)(by + ty + i) * C + bx + tx];
    __syncthreads();
    for (int i = 0; i < 32; i += 8)
        out[(size_t)(bx + ty + i) * R + by + tx] = (bf16)tile[tx][ty + i];
}

// ---------------- GEMM1: X[4096,1024] @ Wqkv -> scatter Q,K,VT (bf16) ----------------
__global__ __launch_bounds__(256) void gemm_qkv_kernel(
    const bf16* __restrict__ A, const bf16* __restrict__ BT,
    const float* __restrict__ bias,
    bf16* __restrict__ Q, bf16* __restrict__ K, bf16* __restrict__ VT) {
    __shared__ __attribute__((aligned(16))) char lds[2][16384];  // A[0,8K) B[8K,16K)
    int bm = blockIdx.x, bn = blockIdx.y;
    int t = threadIdx.x;
    int w = t >> 6, lane = t & 63, g = lane >> 4, l16 = lane & 15;
    int wm = (w >> 1) * 64, wn = (w & 1) * 64;
    f32x4 acc[4][4] = {};
    const bf16* Ablk = A + (size_t)(bm * 128) * 1024;
    const bf16* Bblk = BT + (size_t)(bn * 128) * 1024;
    int srow = t >> 2;
    int scg = (t & 3) ^ (srow & 3);
    const bf16* ag0 = Ablk + (size_t)srow * 1024 + scg * 8;
    const bf16* ag1 = ag0 + 64 * 1024;
    const bf16* bg0 = Bblk + (size_t)srow * 1024 + scg * 8;
    const bf16* bg1 = bg0 + 64 * 1024;

    load_lds16(ag0, lds[0] + t * 16);
    load_lds16(ag1, lds[0] + 4096 + t * 16);
    load_lds16(bg0, lds[0] + 8192 + t * 16);
    load_lds16(bg1, lds[0] + 12288 + t * 16);
    asm volatile("s_waitcnt vmcnt(0)" ::: "memory");

    int sw = l16 & 3;
#pragma unroll 2
    for (int j = 0; j < 32; j++) {
        asm volatile("s_barrier" ::: "memory");
        int jp = j + 1 < 32 ? j + 1 : 31;
        char* dst = lds[(j + 1) & 1];
        load_lds16(ag0 + jp * 32, dst + t * 16);
        load_lds16(ag1 + jp * 32, dst + 4096 + t * 16);
        load_lds16(bg0 + jp * 32, dst + 8192 + t * 16);
        load_lds16(bg1 + jp * 32, dst + 12288 + t * 16);

        const bf16* As = (const bf16*)lds[j & 1];
        const bf16* Bs = (const bf16*)(lds[j & 1] + 8192);
        bf16x8 af[4], bfr[4];
#pragma unroll
        for (int mi = 0; mi < 4; mi++) {
            int row = wm + mi * 16 + l16;
            af[mi] = *(const bf16x8*)(&As[row * 32 + (g ^ sw) * 8]);
        }
#pragma unroll
        for (int ni = 0; ni < 4; ni++) {
            int row = wn + ni * 16 + l16;
            bfr[ni] = *(const bf16x8*)(&Bs[row * 32 + (g ^ sw) * 8]);
        }
#pragma unroll
        for (int mi = 0; mi < 4; mi++)
#pragma unroll
            for (int ni = 0; ni < 4; ni++)
                acc[mi][ni] = MFMA(bfr[ni], af[mi], acc[mi][ni]);  // D^T
        asm volatile("s_waitcnt vmcnt(0)" ::: "memory");
    }
    __syncthreads();  // publish all DMA before LDS reuse as vtile

    bf16* vt = (bf16*)lds;  // V-half transpose tile [64 d][136 s]
    int b = bm >> 4;
    int row0 = (bm & 15) * 128 + wm;
    int half_col = bn * 128 + wn;
    int h = half_col / 192, tt = half_col % 192;  // wave-uniform
    size_t bh = (size_t)(b * 16 + h);

    if (tt < 128) {
        bf16* base = (tt == 0 ? Q : K) + bh * 2048 * 64;
#pragma unroll
        for (int mi = 0; mi < 4; mi++) {
#pragma unroll
            for (int ni = 0; ni < 4; ni++) {
                int d0 = ni * 16 + g * 4;
                float4 bv = *(const float4*)(&bias[half_col + d0]);
                int s = row0 + mi * 16 + l16;
                bf16x4 pk = {(bf16)(acc[mi][ni][0] + bv.x), (bf16)(acc[mi][ni][1] + bv.y),
                             (bf16)(acc[mi][ni][2] + bv.z), (bf16)(acc[mi][ni][3] + bv.w)};
                *(bf16x4*)(&base[(size_t)s * 64 + d0]) = pk;
            }
        }
    } else {
#pragma unroll
        for (int mi = 0; mi < 4; mi++) {
            int s_local = wm + mi * 16 + l16;
#pragma unroll
            for (int ni = 0; ni < 4; ni++) {
                int d0 = ni * 16 + g * 4;
                float4 bv = *(const float4*)(&bias[half_col + d0]);
                vt[(d0 + 0) * 136 + s_local] = (bf16)(acc[mi][ni][0] + bv.x);
                vt[(d0 + 1) * 136 + s_local] = (bf16)(acc[mi][ni][1] + bv.y);
                vt[(d0 + 2) * 136 + s_local] = (bf16)(acc[mi][ni][2] + bv.z);
                vt[(d0 + 3) * 136 + s_local] = (bf16)(acc[mi][ni][3] + bv.w);
            }
        }
    }
    __syncthreads();

    int hc0 = bn * 128, hc1 = bn * 128 + 64;
    int vhalf = (hc0 % 192 == 128) ? 0 : ((hc1 % 192 == 128) ? 1 : -1);
    if (vhalf >= 0) {
        int vcol = bn * 128 + vhalf * 64;
        size_t vbh = (size_t)(b * 16 + vcol / 192);
        int d = t >> 2, ch = t & 3;
        const bf16* src = &vt[d * 136 + ch * 32];
        bf16* dstp = &VT[(vbh * 64 + d) * 2048 + (bm & 15) * 128 + ch * 32];
#pragma unroll
        for (int k = 0; k < 4; k++)
            *(bf16x8*)(&dstp[k * 8]) = *(const bf16x8*)(&src[k * 8]);
    }
}

// ---------------- GEMM3: vals[4096,1024] @ Wout -> out fp32 ----------------
__global__ __launch_bounds__(256) void gemm_out_kernel(
    const bf16* __restrict__ A, const bf16* __restrict__ BT,
    const float* __restrict__ bias, float* __restrict__ out) {
    __shared__ __attribute__((aligned(16))) char lds[2][12288];  // A[0,8K) B[8K,12K)
    int bm = blockIdx.x, bn = blockIdx.y;
    int t = threadIdx.x;
    int w = t >> 6, lane = t & 63, g = lane >> 4, l16 = lane & 15;
    int wm = (w >> 1) * 64, wn = (w & 1) * 32;
    f32x4 acc[4][2] = {};
    const bf16* Ablk = A + (size_t)(bm * 128) * 1024;
    const bf16* Bblk = BT + (size_t)(bn * 64) * 1024;
    int srow = t >> 2;
    int scg = (t & 3) ^ (srow & 3);
    const bf16* ag0 = Ablk + (size_t)srow * 1024 + scg * 8;
    const bf16* ag1 = ag0 + 64 * 1024;
    const bf16* bg0 = Bblk + (size_t)srow * 1024 + scg * 8;

    load_lds16(ag0, lds[0] + t * 16);
    load_lds16(ag1, lds[0] + 4096 + t * 16);
    load_lds16(bg0, lds[0] + 8192 + t * 16);
    asm volatile("s_waitcnt vmcnt(0)" ::: "memory");

    int sw = l16 & 3;
#pragma unroll 2
    for (int j = 0; j < 32; j++) {
        asm volatile("s_barrier" ::: "memory");
        int jp = j + 1 < 32 ? j + 1 : 31;
        char* dst = lds[(j + 1) & 1];
        load_lds16(ag0 + jp * 32, dst + t * 16);
        load_lds16(ag1 + jp * 32, dst + 4096 + t * 16);
        load_lds16(bg0 + jp * 32, dst + 8192 + t * 16);

        const bf16* As = (const bf16*)lds[j & 1];
        const bf16* Bs = (const bf16*)(lds[j & 1] + 8192);
        bf16x8 af[4], bfr[2];
#pragma unroll
        for (int mi = 0; mi < 4; mi++) {
            int row = wm + mi * 16 + l16;
            af[mi] = *(const bf16x8*)(&As[row * 32 + (g ^ sw) * 8]);
        }
#pragma unroll
        for (int ni = 0; ni < 2; ni++) {
            int row = wn + ni * 16 + l16;
            bfr[ni] = *(const bf16x8*)(&Bs[row * 32 + (g ^ sw) * 8]);
        }
#pragma unroll
        for (int mi = 0; mi < 4; mi++)
#pragma unroll
            for (int ni = 0; ni < 2; ni++)
                acc[mi][ni] = MFMA(bfr[ni], af[mi], acc[mi][ni]);  // D^T
        asm volatile("s_waitcnt vmcnt(0)" ::: "memory");
    }

#pragma unroll
    for (int mi = 0; mi < 4; mi++) {
#pragma unroll
        for (int ni = 0; ni < 2; ni++) {
            int row = bm * 128 + wm + mi * 16 + l16;
            int col0 = bn * 64 + wn + ni * 16 + g * 4;
            float4 bv = *(const float4*)(&bias[col0]);
            float4 ov = {acc[mi][ni][0] + bv.x, acc[mi][ni][1] + bv.y,
                         acc[mi][ni][2] + bv.z, acc[mi][ni][3] + bv.w};
            *(float4*)(&out[(size_t)row * 1024 + col0]) = ov;
        }
    }
}

// ---------------- flash attention (R12: BK=64, 32 q-rows per wave) ----------------
// grid = 512 (32 bh x 16 q-tiles of 128), block = 256 (4 waves x 32 q).
// BK=64, 32 iters, two 32-k halves per iter with no barrier between.
// 4 LDS bufs x 16KB (K[0,8K): rows 0..63 row-major; V[8K,16K): two 4KB halves).
// Per iter: 8 mask float4 + 4 DMA -> vmcnt(24) keeps 2 iters in flight.
// Static-max softmax (scores bounded); per-lane l, reduced once at end.
__global__ __launch_bounds__(256, 2) void attn_kernel(
    const bf16* __restrict__ Q, const bf16* __restrict__ K,
    const bf16* __restrict__ VT, const float* __restrict__ mask,
    bf16* __restrict__ vals) {
    __shared__ __attribute__((aligned(16))) char lds[4][16384];  // [buf]: K[0,8K) V[8K,16K)

    int blk = blockIdx.x;
    int bh = ((blk & 7) << 2) | ((blk >> 3) & 3);
    int qt = blk >> 5;                      // 0..15
    int t = threadIdx.x;
    int w = t >> 6, lane = t & 63, g = lane >> 4, l16 = lane & 15;
    int qw = qt * 128 + w * 32;             // wave's 32-q base

    const bf16* Qp = Q + (size_t)bh * 2048 * 64;
    const bf16* Kp = K + (size_t)bh * 2048 * 64;
    const bf16* Vp = VT + (size_t)bh * 64 * 2048;
    const float* mrowA = mask + (size_t)(qw + l16) * 2048;        // q-group 0
    const float* mrowB = mask + (size_t)(qw + 16 + l16) * 2048;   // q-group 1

    int ks_row = t >> 3;                    // 0..31
    int ks_cblk = (t & 7) ^ (ks_row & 7);
    const bf16* kg = Kp + ks_row * 64 + ks_cblk * 8;
    int vs_d = t >> 2;                      // 0..63
    int vs_sblk = (t & 3) ^ ((t >> 3) & 3);
    const bf16* vg = Vp + (size_t)vs_d * 2048 + vs_sblk * 8;

    const float SCL = 0.125f * 1.44269504089f;
    const float L2E = 1.44269504089f;

    // Q B-frags for both q-groups, two d-halves each
    bf16x8 qa0 = *(const bf16x8*)(&Qp[(size_t)(qw + l16) * 64 + g * 8]);
    bf16x8 qa1 = *(const bf16x8*)(&Qp[(size_t)(qw + l16) * 64 + 32 + g * 8]);
    bf16x8 qb0 = *(const bf16x8*)(&Qp[(size_t)(qw + 16 + l16) * 64 + g * 8]);
    bf16x8 qb1 = *(const bf16x8*)(&Qp[(size_t)(qw + 16 + l16) * 64 + 32 + g * 8]);

    // stage iter 0 (K rows 0..31, 32..63; V s 0..31, 32..63)
    load_lds16(kg + 0,       lds[0] + t * 16);
    load_lds16(kg + 32 * 64, lds[0] + 4096 + t * 16);
    load_lds16(vg + 0,       lds[0] + 8192 + t * 16);
    load_lds16(vg + 32,      lds[0] + 12288 + t * 16);
    // mask for iter 0: 4 col-blocks per q-group
    float4 mva0 = *(const float4*)(&mrowA[0 + g * 4]);
    float4 mva1 = *(const float4*)(&mrowA[16 + g * 4]);
    float4 mva2 = *(const float4*)(&mrowA[32 + g * 4]);
    float4 mva3 = *(const float4*)(&mrowA[48 + g * 4]);
    float4 mvb0 = *(const float4*)(&mrowB[0 + g * 4]);
    float4 mvb1 = *(const float4*)(&mrowB[16 + g * 4]);
    float4 mvb2 = *(const float4*)(&mrowB[32 + g * 4]);
    float4 mvb3 = *(const float4*)(&mrowB[48 + g * 4]);
    // stage iter 1
    load_lds16(kg + 64 * 64,           lds[1] + t * 16);
    load_lds16(kg + 64 * 64 + 32 * 64, lds[1] + 4096 + t * 16);
    load_lds16(vg + 64,                lds[1] + 8192 + t * 16);
    load_lds16(vg + 64 + 32,           lds[1] + 12288 + t * 16);
    asm volatile("s_waitcnt vmcnt(0)" ::: "memory");
    asm volatile("s_barrier" ::: "memory");

    f32x4 o[4][2] = {};
    float la = 0.f, lb = 0.f;

    for (int j = 0; j < 32; j++) {
        const char* bufp = lds[j & 3];
        int jm = j + 1 < 32 ? j + 1 : 31;
        float4 nmva0 = *(const float4*)(&mrowA[jm * 64 + 0 + g * 4]);
        float4 nmva1 = *(const float4*)(&mrowA[jm * 64 + 16 + g * 4]);
        float4 nmva2 = *(const float4*)(&mrowA[jm * 64 + 32 + g * 4]);
        float4 nmva3 = *(const float4*)(&mrowA[jm * 64 + 48 + g * 4]);
        float4 nmvb0 = *(const float4*)(&mrowB[jm * 64 + 0 + g * 4]);
        float4 nmvb1 = *(const float4*)(&mrowB[jm * 64 + 16 + g * 4]);
        float4 nmvb2 = *(const float4*)(&mrowB[jm * 64 + 32 + g * 4]);
        float4 nmvb3 = *(const float4*)(&mrowB[jm * 64 + 48 + g * 4]);
        int jp = j + 2 < 32 ? j + 2 : 31;
        char* dstp = lds[(j + 2) & 3];
        load_lds16(kg + (size_t)jp * 64 * 64,           dstp + t * 16);
        load_lds16(kg + (size_t)jp * 64 * 64 + 32 * 64, dstp + 4096 + t * 16);
        load_lds16(vg + jp * 64,                        dstp + 8192 + t * 16);
        load_lds16(vg + jp * 64 + 32,                   dstp + 12288 + t * 16);
        // per-iter segment = 12 vmem (8 mask + 4 DMA); keep 2 iters in flight
        asm volatile("s_waitcnt vmcnt(24)" ::: "memory");
        asm volatile("s_barrier" ::: "memory");

#pragma unroll
        for (int h = 0; h < 2; h++) {
            float pa[8], pb[8];
#pragma unroll
            for (int tsub = 0; tsub < 2; tsub++) {
                int ts = h * 2 + tsub;
                int s0 = ts * 16 + l16;       // 0..63 within K tile
                int swz = s0 & 7;
                bf16x8 k0 = *(const bf16x8*)(&bufp[(s0 * 8 + (g ^ swz)) * 16]);
                bf16x8 k1 = *(const bf16x8*)(&bufp[(s0 * 8 + ((4 + g) ^ swz)) * 16]);
                f32x4 sta = {}, stb = {};
                sta = MFMA(k0, qa0, sta);
                sta = MFMA(k1, qa1, sta);
                stb = MFMA(k0, qb0, stb);
                stb = MFMA(k1, qb1, stb);
                float4 ma = (h == 0) ? (tsub ? mva1 : mva0) : (tsub ? mva3 : mva2);
                float4 mb = (h == 0) ? (tsub ? mvb1 : mvb0) : (tsub ? mvb3 : mvb2);
                pa[tsub * 4 + 0] = EXP2(sta[0] * SCL + ma.x * L2E);
                pa[tsub * 4 + 1] = EXP2(sta[1] * SCL + ma.y * L2E);
                pa[tsub * 4 + 2] = EXP2(sta[2] * SCL + ma.z * L2E);
                pa[tsub * 4 + 3] = EXP2(sta[3] * SCL + ma.w * L2E);
                pb[tsub * 4 + 0] = EXP2(stb[0] * SCL + mb.x * L2E);
                pb[tsub * 4 + 1] = EXP2(stb[1] * SCL + mb.y * L2E);
                pb[tsub * 4 + 2] = EXP2(stb[2] * SCL + mb.z * L2E);
                pb[tsub * 4 + 3] = EXP2(stb[3] * SCL + mb.w * L2E);
            }
#pragma unroll
            for (int i = 0; i < 8; i++) { la += pa[i]; lb += pb[i]; }

            // P C-layout -> B-frag via shfl (destination-side ts select), per group
            int selA = (((2 * g) & 3) << 4) | l16;
            int selB = (((2 * g + 1) & 3) << 4) | l16;
            bool hi = (g & 2) != 0;
            union { int i[4]; bf16x8 v; } pua, pub;
            {
                union { bf16x2 hh; int i; } u;
                int dw0, dw1, dw2, dw3;
                u.hh = bf16x2{(bf16)pa[0], (bf16)pa[1]}; dw0 = u.i;
                u.hh = bf16x2{(bf16)pa[2], (bf16)pa[3]}; dw1 = u.i;
                u.hh = bf16x2{(bf16)pa[4], (bf16)pa[5]}; dw2 = u.i;
                u.hh = bf16x2{(bf16)pa[6], (bf16)pa[7]}; dw3 = u.i;
                int t0a = __shfl(dw0, selA, 64), t2a = __shfl(dw2, selA, 64);
                int t1a = __shfl(dw1, selA, 64), t3a = __shfl(dw3, selA, 64);
                int t0b = __shfl(dw0, selB, 64), t2b = __shfl(dw2, selB, 64);
                int t1b = __shfl(dw1, selB, 64), t3b = __shfl(dw3, selB, 64);
                pua.i[0] = hi ? t2a : t0a;
                pua.i[1] = hi ? t3a : t1a;
                pua.i[2] = hi ? t2b : t0b;
                pua.i[3] = hi ? t3b : t1b;
            }
            {
                union { bf16x2 hh; int i; } u;
                int dw0, dw1, dw2, dw3;
                u.hh = bf16x2{(bf16)pb[0], (bf16)pb[1]}; dw0 = u.i;
                u.hh = bf16x2{(bf16)pb[2], (bf16)pb[3]}; dw1 = u.i;
                u.hh = bf16x2{(bf16)pb[4], (bf16)pb[5]}; dw2 = u.i;
                u.hh = bf16x2{(bf16)pb[6], (bf16)pb[7]}; dw3 = u.i;
                int t0a = __shfl(dw0, selA, 64), t2a = __shfl(dw2, selA, 64);
                int t1a = __shfl(dw1, selA, 64), t3a = __shfl(dw3, selA, 64);
                int t0b = __shfl(dw0, selB, 64), t2b = __shfl(dw2, selB, 64);
                int t1b = __shfl(dw1, selB, 64), t3b = __shfl(dw3, selB, 64);
                pub.i[0] = hi ? t2a : t0a;
                pub.i[1] = hi ? t3a : t1a;
                pub.i[2] = hi ? t2b : t0b;
                pub.i[3] = hi ? t3b : t1b;
            }

            // O^T += V^T · P  (V half h at 8192 + h*4096)
#pragma unroll
            for (int nc = 0; nc < 4; nc++) {
                int d = nc * 16 + l16;
                int slot = d * 4 + (g ^ ((d >> 1) & 3));
                bf16x8 vf = *(const bf16x8*)(&bufp[8192 + h * 4096 + slot * 16]);
                o[nc][0] = MFMA(vf, pua.v, o[nc][0]);
                o[nc][1] = MFMA(vf, pub.v, o[nc][1]);
            }
        }

        mva0 = nmva0; mva1 = nmva1; mva2 = nmva2; mva3 = nmva3;
        mvb0 = nmvb0; mvb1 = nmvb1; mvb2 = nmvb2; mvb3 = nmvb3;
    }
    asm volatile("s_waitcnt vmcnt(0)" ::: "memory");

    la += __shfl_xor(la, 16, 64);
    la += __shfl_xor(la, 32, 64);
    lb += __shfl_xor(lb, 16, 64);
    lb += __shfl_xor(lb, 32, 64);
    int b = bh >> 4, h = bh & 15;
    float lia = 1.f / la, lib = 1.f / lb;
    size_t rowA = (size_t)(b * 2048 + qw + l16);
    size_t rowB = rowA + 16;
#pragma unroll
    for (int nc = 0; nc < 4; nc++) {
        bf16x4 pkA = {(bf16)(o[nc][0][0] * lia), (bf16)(o[nc][0][1] * lia),
                      (bf16)(o[nc][0][2] * lia), (bf16)(o[nc][0][3] * lia)};
        *(bf16x4*)(&vals[rowA * 1024 + h * 64 + nc * 16 + g * 4]) = pkA;
        bf16x4 pkB = {(bf16)(o[nc][1][0] * lib), (bf16)(o[nc][1][1] * lib),
                      (bf16)(o[nc][1][2] * lib), (bf16)(o[nc][1][3] * lib)};
        *(bf16x4*)(&vals[rowB * 1024 + h * 64 + nc * 16 + g * 4]) = pkB;
    }
}

// ---------------- launch ----------------
extern "C" void kernel_launch(void* const* d_in, const int* in_sizes, int n_in,
                              void* d_out, int out_size, void* d_ws, size_t ws_size,
                              hipStream_t stream) {
    const float* x     = (const float*)d_in[0];
    const float* mask  = (const float*)d_in[1];
    const float* w_qkv = (const float*)d_in[2];
    const float* b_qkv = (const float*)d_in[3];
    const float* w_out = (const float*)d_in[4];
    const float* b_out = (const float*)d_in[5];
    float* out = (float*)d_out;

    char* ws = (char*)d_ws;
    size_t off = 0;
    bf16* xb    = (bf16*)(ws + off); off += (size_t)4096 * 1024 * 2;
    bf16* wqkvT = (bf16*)(ws + off); off += (size_t)3072 * 1024 * 2;
    bf16* woutT = (bf16*)(ws + off); off += (size_t)1024 * 1024 * 2;
    bf16* Qa    = (bf16*)(ws + off); off += (size_t)32 * 2048 * 64 * 2;
    bf16* Ka    = (bf16*)(ws + off); off += (size_t)32 * 2048 * 64 * 2;
    bf16* VTa   = (bf16*)(ws + off); off += (size_t)32 * 64 * 2048 * 2;
    bf16* vals  = (bf16*)(ws + off); off += (size_t)4096 * 1024 * 2;

    cast4_kernel<<<4096, 256, 0, stream>>>(x, xb, 4096 * 1024 / 4);
    transpose_cast_kernel<<<dim3(96, 32), dim3(32, 8), 0, stream>>>(w_qkv, wqkvT, 1024, 3072);
    transpose_cast_kernel<<<dim3(32, 32), dim3(32, 8), 0, stream>>>(w_out, woutT, 1024, 1024);
    gemm_qkv_kernel<<<dim3(32, 24), 256, 0, stream>>>(xb, wqkvT, b_qkv, Qa, Ka, VTa);
    attn_kernel<<<512, 256, 0, stream>>>(Qa, Ka, VTa, mask, vals);
    gemm_out_kernel<<<dim3(32, 16), 256, 0, stream>>>(vals, woutT, b_out, out);
}

// Round 6
// 225.273 us; speedup vs baseline: 1.0860x; 1.0860x over previous
//
#include <hip/hip_runtime.h>

// MHA: B=2, S=2048, D=1024, H=16, hd=64. fp32 in/out, bf16 MFMA internally.
// R15: 32x32-MFMA attn (R14 structure) with the P->PV repack done via
// 8 __shfl_xor(32) + selects instead of 4 v_permlane32_swap. R14's 2.1e-2
// absmax triangulates to a misrouted permlane (output write + C-formula
// validated by error magnitude; frag layouts permutation-robust). Shuffle
// semantics are exact; still halves shuffle count vs R9 (8 vs 16/iter),
// halves MFMA instruction count, 1-step l-reduce, 32KB LDS.
// LDS/staging identical to R9: 4 bufs x 8KB (K 4K + V 4K), dist-2 prefetch,
// 6 vmem/segment (4 mask + 2 DMA) -> vmcnt(12). GEMMs unchanged.

typedef __bf16 bf16;
typedef __bf16 bf16x2 __attribute__((ext_vector_type(2)));
typedef __bf16 bf16x4 __attribute__((ext_vector_type(4)));
typedef __bf16 bf16x8 __attribute__((ext_vector_type(8)));
typedef float f32x4 __attribute__((ext_vector_type(4)));
typedef float f32x16 __attribute__((ext_vector_type(16)));

#define MFMA(a, b, c) __builtin_amdgcn_mfma_f32_16x16x32_bf16((a), (b), (c), 0, 0, 0)
#define MFMA32(a, b, c) __builtin_amdgcn_mfma_f32_32x32x16_bf16((a), (b), (c), 0, 0, 0)

#if __has_builtin(__builtin_amdgcn_exp2f)
#define EXP2(x) __builtin_amdgcn_exp2f(x)
#else
#define EXP2(x) exp2f(x)
#endif

__device__ __forceinline__ void load_lds16(const bf16* g, void* l) {
    __builtin_amdgcn_global_load_lds(
        (const __attribute__((address_space(1))) unsigned int*)g,
        (__attribute__((address_space(3))) unsigned int*)l, 16, 0, 0);
}

// ---------------- cast fp32 -> bf16, 4 elems/thread ----------------
__global__ void cast4_kernel(const float* __restrict__ in, bf16* __restrict__ out, int n4) {
    int i = blockIdx.x * blockDim.x + threadIdx.x;
    if (i < n4) {
        float4 v = ((const float4*)in)[i];
        bf16x4 o = {(bf16)v.x, (bf16)v.y, (bf16)v.z, (bf16)v.w};
        ((bf16x4*)out)[i] = o;
    }
}

// ---------------- transpose + cast: in [R,C] fp32 -> out [C,R] bf16 ----------------
__global__ void transpose_cast_kernel(const float* __restrict__ in, bf16* __restrict__ out,
                                      int R, int C) {
    __shared__ float tile[32][33];
    int bx = blockIdx.x * 32;
    int by = blockIdx.y * 32;
    int tx = threadIdx.x, ty = threadIdx.y;  // (32,8)
    for (int i = 0; i < 32; i += 8)
        tile[ty + i][tx] = in[(size_t)(by + ty + i) * C + bx + tx];
    __syncthreads();
    for (int i = 0; i < 32; i += 8)
        out[(size_t)(bx + ty + i) * R + by + tx] = (bf16)tile[tx][ty + i];
}

// ---------------- GEMM1: X[4096,1024] @ Wqkv -> scatter Q,K,VT (bf16) ----------------
__global__ __launch_bounds__(256) void gemm_qkv_kernel(
    const bf16* __restrict__ A, const bf16* __restrict__ BT,
    const float* __restrict__ bias,
    bf16* __restrict__ Q, bf16* __restrict__ K, bf16* __restrict__ VT) {
    __shared__ __attribute__((aligned(16))) char lds[2][16384];  // A[0,8K) B[8K,16K)
    int bm = blockIdx.x, bn = blockIdx.y;
    int t = threadIdx.x;
    int w = t >> 6, lane = t & 63, g = lane >> 4, l16 = lane & 15;
    int wm = (w >> 1) * 64, wn = (w & 1) * 64;
    f32x4 acc[4][4] = {};
    const bf16* Ablk = A + (size_t)(bm * 128) * 1024;
    const bf16* Bblk = BT + (size_t)(bn * 128) * 1024;
    int srow = t >> 2;
    int scg = (t & 3) ^ (srow & 3);
    const bf16* ag0 = Ablk + (size_t)srow * 1024 + scg * 8;
    const bf16* ag1 = ag0 + 64 * 1024;
    const bf16* bg0 = Bblk + (size_t)srow * 1024 + scg * 8;
    const bf16* bg1 = bg0 + 64 * 1024;

    load_lds16(ag0, lds[0] + t * 16);
    load_lds16(ag1, lds[0] + 4096 + t * 16);
    load_lds16(bg0, lds[0] + 8192 + t * 16);
    load_lds16(bg1, lds[0] + 12288 + t * 16);
    asm volatile("s_waitcnt vmcnt(0)" ::: "memory");

    int sw = l16 & 3;
#pragma unroll 2
    for (int j = 0; j < 32; j++) {
        asm volatile("s_barrier" ::: "memory");
        int jp = j + 1 < 32 ? j + 1 : 31;
        char* dst = lds[(j + 1) & 1];
        load_lds16(ag0 + jp * 32, dst + t * 16);
        load_lds16(ag1 + jp * 32, dst + 4096 + t * 16);
        load_lds16(bg0 + jp * 32, dst + 8192 + t * 16);
        load_lds16(bg1 + jp * 32, dst + 12288 + t * 16);

        const bf16* As = (const bf16*)lds[j & 1];
        const bf16* Bs = (const bf16*)(lds[j & 1] + 8192);
        bf16x8 af[4], bfr[4];
#pragma unroll
        for (int mi = 0; mi < 4; mi++) {
            int row = wm + mi * 16 + l16;
            af[mi] = *(const bf16x8*)(&As[row * 32 + (g ^ sw) * 8]);
        }
#pragma unroll
        for (int ni = 0; ni < 4; ni++) {
            int row = wn + ni * 16 + l16;
            bfr[ni] = *(const bf16x8*)(&Bs[row * 32 + (g ^ sw) * 8]);
        }
#pragma unroll
        for (int mi = 0; mi < 4; mi++)
#pragma unroll
            for (int ni = 0; ni < 4; ni++)
                acc[mi][ni] = MFMA(bfr[ni], af[mi], acc[mi][ni]);  // D^T
        asm volatile("s_waitcnt vmcnt(0)" ::: "memory");
    }
    __syncthreads();  // publish all DMA before LDS reuse as vtile

    bf16* vt = (bf16*)lds;  // V-half transpose tile [64 d][136 s]
    int b = bm >> 4;
    int row0 = (bm & 15) * 128 + wm;
    int half_col = bn * 128 + wn;
    int h = half_col / 192, tt = half_col % 192;  // wave-uniform
    size_t bh = (size_t)(b * 16 + h);

    if (tt < 128) {
        bf16* base = (tt == 0 ? Q : K) + bh * 2048 * 64;
#pragma unroll
        for (int mi = 0; mi < 4; mi++) {
#pragma unroll
            for (int ni = 0; ni < 4; ni++) {
                int d0 = ni * 16 + g * 4;
                float4 bv = *(const float4*)(&bias[half_col + d0]);
                int s = row0 + mi * 16 + l16;
                bf16x4 pk = {(bf16)(acc[mi][ni][0] + bv.x), (bf16)(acc[mi][ni][1] + bv.y),
                             (bf16)(acc[mi][ni][2] + bv.z), (bf16)(acc[mi][ni][3] + bv.w)};
                *(bf16x4*)(&base[(size_t)s * 64 + d0]) = pk;
            }
        }
    } else {
#pragma unroll
        for (int mi = 0; mi < 4; mi++) {
            int s_local = wm + mi * 16 + l16;
#pragma unroll
            for (int ni = 0; ni < 4; ni++) {
                int d0 = ni * 16 + g * 4;
                float4 bv = *(const float4*)(&bias[half_col + d0]);
                vt[(d0 + 0) * 136 + s_local] = (bf16)(acc[mi][ni][0] + bv.x);
                vt[(d0 + 1) * 136 + s_local] = (bf16)(acc[mi][ni][1] + bv.y);
                vt[(d0 + 2) * 136 + s_local] = (bf16)(acc[mi][ni][2] + bv.z);
                vt[(d0 + 3) * 136 + s_local] = (bf16)(acc[mi][ni][3] + bv.w);
            }
        }
    }
    __syncthreads();

    int hc0 = bn * 128, hc1 = bn * 128 + 64;
    int vhalf = (hc0 % 192 == 128) ? 0 : ((hc1 % 192 == 128) ? 1 : -1);
    if (vhalf >= 0) {
        int vcol = bn * 128 + vhalf * 64;
        size_t vbh = (size_t)(b * 16 + vcol / 192);
        int d = t >> 2, ch = t & 3;
        const bf16* src = &vt[d * 136 + ch * 32];
        bf16* dstp = &VT[(vbh * 64 + d) * 2048 + (bm & 15) * 128 + ch * 32];
#pragma unroll
        for (int k = 0; k < 4; k++)
            *(bf16x8*)(&dstp[k * 8]) = *(const bf16x8*)(&src[k * 8]);
    }
}

// ---------------- GEMM3: vals[4096,1024] @ Wout -> out fp32 ----------------
__global__ __launch_bounds__(256) void gemm_out_kernel(
    const bf16* __restrict__ A, const bf16* __restrict__ BT,
    const float* __restrict__ bias, float* __restrict__ out) {
    __shared__ __attribute__((aligned(16))) char lds[2][12288];  // A[0,8K) B[8K,12K)
    int bm = blockIdx.x, bn = blockIdx.y;
    int t = threadIdx.x;
    int w = t >> 6, lane = t & 63, g = lane >> 4, l16 = lane & 15;
    int wm = (w >> 1) * 64, wn = (w & 1) * 32;
    f32x4 acc[4][2] = {};
    const bf16* Ablk = A + (size_t)(bm * 128) * 1024;
    const bf16* Bblk = BT + (size_t)(bn * 64) * 1024;
    int srow = t >> 2;
    int scg = (t & 3) ^ (srow & 3);
    const bf16* ag0 = Ablk + (size_t)srow * 1024 + scg * 8;
    const bf16* ag1 = ag0 + 64 * 1024;
    const bf16* bg0 = Bblk + (size_t)srow * 1024 + scg * 8;

    load_lds16(ag0, lds[0] + t * 16);
    load_lds16(ag1, lds[0] + 4096 + t * 16);
    load_lds16(bg0, lds[0] + 8192 + t * 16);
    asm volatile("s_waitcnt vmcnt(0)" ::: "memory");

    int sw = l16 & 3;
#pragma unroll 2
    for (int j = 0; j < 32; j++) {
        asm volatile("s_barrier" ::: "memory");
        int jp = j + 1 < 32 ? j + 1 : 31;
        char* dst = lds[(j + 1) & 1];
        load_lds16(ag0 + jp * 32, dst + t * 16);
        load_lds16(ag1 + jp * 32, dst + 4096 + t * 16);
        load_lds16(bg0 + jp * 32, dst + 8192 + t * 16);

        const bf16* As = (const bf16*)lds[j & 1];
        const bf16* Bs = (const bf16*)(lds[j & 1] + 8192);
        bf16x8 af[4], bfr[2];
#pragma unroll
        for (int mi = 0; mi < 4; mi++) {
            int row = wm + mi * 16 + l16;
            af[mi] = *(const bf16x8*)(&As[row * 32 + (g ^ sw) * 8]);
        }
#pragma unroll
        for (int ni = 0; ni < 2; ni++) {
            int row = wn + ni * 16 + l16;
            bfr[ni] = *(const bf16x8*)(&Bs[row * 32 + (g ^ sw) * 8]);
        }
#pragma unroll
        for (int mi = 0; mi < 4; mi++)
#pragma unroll
            for (int ni = 0; ni < 2; ni++)
                acc[mi][ni] = MFMA(bfr[ni], af[mi], acc[mi][ni]);  // D^T
        asm volatile("s_waitcnt vmcnt(0)" ::: "memory");
    }

#pragma unroll
    for (int mi = 0; mi < 4; mi++) {
#pragma unroll
        for (int ni = 0; ni < 2; ni++) {
            int row = bm * 128 + wm + mi * 16 + l16;
            int col0 = bn * 64 + wn + ni * 16 + g * 4;
            float4 bv = *(const float4*)(&bias[col0]);
            float4 ov = {acc[mi][ni][0] + bv.x, acc[mi][ni][1] + bv.y,
                         acc[mi][ni][2] + bv.z, acc[mi][ni][3] + bv.w};
            *(float4*)(&out[(size_t)row * 1024 + col0]) = ov;
        }
    }
}

// ---------------- flash attention (R15: 32x32 MFMA, shfl-xor repack) ----------------
// grid = 512 (32 bh x 16 q-tiles of 128), block = 256 (4 waves x 32 q).
// Lane owns q = qw + (lane&31); hi = lane>>5 splits k/d chunks.
// QK^T: S^T[k][q] via 4 chained MFMA32 over d-tiles; C-layout: col=q=lane&31,
// row=k=(r&3)+8*(r>>2)+4*hi.
// P repack: dw[i]=(p[2i],p[2i+1]); partner via __shfl_xor(32); select by hi:
//   kc0 frag = [hi?sx2:dw0, hi?sx3:dw1, hi?dw2:sx0, hi?dw3:sx1], kc1 same +4.
// PV: O^T[d][q] += MFMA32(V^T_frag[dblk][kc], P_frag[kc]).
// LDS/staging identical to R9: 4 bufs x 8KB, dist-2 prefetch, vmcnt(12).
__global__ __launch_bounds__(256, 2) void attn_kernel(
    const bf16* __restrict__ Q, const bf16* __restrict__ K,
    const bf16* __restrict__ VT, const float* __restrict__ mask,
    bf16* __restrict__ vals) {
    __shared__ __attribute__((aligned(16))) char lds[4][8192];  // [buf]: K[0,4K) V[4K,8K)

    int blk = blockIdx.x;
    int bh = ((blk & 7) << 2) | ((blk >> 3) & 3);
    int qt = blk >> 5;                      // 0..15
    int t = threadIdx.x;
    int w = t >> 6, lane = t & 63;
    int l32 = lane & 31, hi = lane >> 5;
    int qw = qt * 128 + w * 32;             // wave's 32-q base

    const bf16* Qp = Q + (size_t)bh * 2048 * 64;
    const bf16* Kp = K + (size_t)bh * 2048 * 64;
    const bf16* Vp = VT + (size_t)bh * 64 * 2048;
    const float* mrow = mask + (size_t)(qw + l32) * 2048;  // lane's q-row

    // staging (identical to R9)
    int ks_row = t >> 3;
    int ks_cblk = (t & 7) ^ (ks_row & 7);
    const bf16* kg = Kp + ks_row * 64 + ks_cblk * 8;
    int vs_d = t >> 2;
    int vs_sblk = (t & 3) ^ ((t >> 3) & 3);
    const bf16* vg = Vp + (size_t)vs_d * 2048 + vs_sblk * 8;

    const float SCL = 0.125f * 1.44269504089f;
    const float L2E = 1.44269504089f;

    // Q B-frags: 4 d-tiles of 16 (lane: col q=l32, rows d = t4*16 + hi*8 + 0..7)
    bf16x8 qf[4];
#pragma unroll
    for (int t4 = 0; t4 < 4; t4++)
        qf[t4] = *(const bf16x8*)(&Qp[(size_t)(qw + l32) * 64 + t4 * 16 + hi * 8]);

    // stage iters 0,1
    load_lds16(kg + 0, lds[0] + t * 16);
    load_lds16(vg + 0, lds[0] + 4096 + t * 16);
    float4 mc0 = *(const float4*)(&mrow[0 + hi * 4]);
    float4 mc1 = *(const float4*)(&mrow[8 + hi * 4]);
    float4 mc2 = *(const float4*)(&mrow[16 + hi * 4]);
    float4 mc3 = *(const float4*)(&mrow[24 + hi * 4]);
    load_lds16(kg + 32 * 64, lds[1] + t * 16);
    load_lds16(vg + 32, lds[1] + 4096 + t * 16);
    asm volatile("s_waitcnt vmcnt(0)" ::: "memory");
    asm volatile("s_barrier" ::: "memory");

    f32x16 o0 = {}, o1 = {};
    const f32x16 kZero = {};
    float la = 0.f;

    for (int j = 0; j < 64; j++) {
        const char* bufp = lds[j & 3];
        int jm = j + 1 < 64 ? j + 1 : 63;
        float4 nm0 = *(const float4*)(&mrow[jm * 32 + 0 + hi * 4]);
        float4 nm1 = *(const float4*)(&mrow[jm * 32 + 8 + hi * 4]);
        float4 nm2 = *(const float4*)(&mrow[jm * 32 + 16 + hi * 4]);
        float4 nm3 = *(const float4*)(&mrow[jm * 32 + 24 + hi * 4]);
        int jp = j + 2 < 64 ? j + 2 : 63;
        char* dstp = lds[(j + 2) & 3];
        load_lds16(kg + (size_t)jp * 32 * 64, dstp + t * 16);
        load_lds16(vg + jp * 32, dstp + 4096 + t * 16);
        // segment = 6 vmem (4 mask + 2 DMA); drain all but segments j-1, j
        asm volatile("s_waitcnt vmcnt(12)" ::: "memory");
        asm volatile("s_barrier" ::: "memory");

        // QK^T: 4 chained MFMAs over d-tiles
        f32x16 s;
        {
            int slot0 = l32 * 8 + ((2 * 0 + hi) ^ (l32 & 7));
            bf16x8 kf0 = *(const bf16x8*)(&bufp[slot0 * 16]);
            s = MFMA32(kf0, qf[0], kZero);
            int slot1 = l32 * 8 + ((2 * 1 + hi) ^ (l32 & 7));
            bf16x8 kf1 = *(const bf16x8*)(&bufp[slot1 * 16]);
            s = MFMA32(kf1, qf[1], s);
            int slot2 = l32 * 8 + ((2 * 2 + hi) ^ (l32 & 7));
            bf16x8 kf2 = *(const bf16x8*)(&bufp[slot2 * 16]);
            s = MFMA32(kf2, qf[2], s);
            int slot3 = l32 * 8 + ((2 * 3 + hi) ^ (l32 & 7));
            bf16x8 kf3 = *(const bf16x8*)(&bufp[slot3 * 16]);
            s = MFMA32(kf3, qf[3], s);
        }

        // softmax: reg r -> k = (r&3) + 8*(r>>2) + 4*hi; mask group r>>2, elem r&3
        float p[16];
        p[0]  = EXP2(s[0] * SCL + mc0.x * L2E);
        p[1]  = EXP2(s[1] * SCL + mc0.y * L2E);
        p[2]  = EXP2(s[2] * SCL + mc0.z * L2E);
        p[3]  = EXP2(s[3] * SCL + mc0.w * L2E);
        p[4]  = EXP2(s[4] * SCL + mc1.x * L2E);
        p[5]  = EXP2(s[5] * SCL + mc1.y * L2E);
        p[6]  = EXP2(s[6] * SCL + mc1.z * L2E);
        p[7]  = EXP2(s[7] * SCL + mc1.w * L2E);
        p[8]  = EXP2(s[8] * SCL + mc2.x * L2E);
        p[9]  = EXP2(s[9] * SCL + mc2.y * L2E);
        p[10] = EXP2(s[10] * SCL + mc2.z * L2E);
        p[11] = EXP2(s[11] * SCL + mc2.w * L2E);
        p[12] = EXP2(s[12] * SCL + mc3.x * L2E);
        p[13] = EXP2(s[13] * SCL + mc3.y * L2E);
        p[14] = EXP2(s[14] * SCL + mc3.z * L2E);
        p[15] = EXP2(s[15] * SCL + mc3.w * L2E);
        {
            float a0 = p[0] + p[1], a1 = p[2] + p[3], a2 = p[4] + p[5], a3 = p[6] + p[7];
            float a4 = p[8] + p[9], a5 = p[10] + p[11], a6 = p[12] + p[13], a7 = p[14] + p[15];
            float b0 = a0 + a1, b1 = a2 + a3, b2 = a4 + a5, b3 = a6 + a7;
            la += (b0 + b1) + (b2 + b3);
        }

        // pack 16 f32 -> 8 dwords: dw[i] = bf16 pair (p[2i], p[2i+1])
        // lane holds k: dw0=(0,1) dw1=(2,3) dw2=(8,9) dw3=(10,11)
        //              dw4=(16,17) dw5=(18,19) dw6=(24,25) dw7=(26,27)  (all +4*hi)
        unsigned dw0, dw1, dw2, dw3, dw4, dw5, dw6, dw7;
        {
            union { bf16x2 h; unsigned u; } u;
            u.h = bf16x2{(bf16)p[0],  (bf16)p[1]};  dw0 = u.u;
            u.h = bf16x2{(bf16)p[2],  (bf16)p[3]};  dw1 = u.u;
            u.h = bf16x2{(bf16)p[4],  (bf16)p[5]};  dw2 = u.u;
            u.h = bf16x2{(bf16)p[6],  (bf16)p[7]};  dw3 = u.u;
            u.h = bf16x2{(bf16)p[8],  (bf16)p[9]};  dw4 = u.u;
            u.h = bf16x2{(bf16)p[10], (bf16)p[11]}; dw5 = u.u;
            u.h = bf16x2{(bf16)p[12], (bf16)p[13]}; dw6 = u.u;
            u.h = bf16x2{(bf16)p[14], (bf16)p[15]}; dw7 = u.u;
        }
        // partner-half values via xor-32 shuffle (exact semantics)
        int sx0 = __shfl_xor((int)dw0, 32, 64);
        int sx1 = __shfl_xor((int)dw1, 32, 64);
        int sx2 = __shfl_xor((int)dw2, 32, 64);
        int sx3 = __shfl_xor((int)dw3, 32, 64);
        int sx4 = __shfl_xor((int)dw4, 32, 64);
        int sx5 = __shfl_xor((int)dw5, 32, 64);
        int sx6 = __shfl_xor((int)dw6, 32, 64);
        int sx7 = __shfl_xor((int)dw7, 32, 64);
        bool hib = hi != 0;
        // B-frag element i -> k = kc*16 + hi*8 + i
        union { unsigned u[4]; bf16x8 v; } pb0, pb1;
        pb0.u[0] = hib ? (unsigned)sx2 : dw0;  // el(0,1): lo k(0,1) | hi k(8,9)
        pb0.u[1] = hib ? (unsigned)sx3 : dw1;  // el(2,3): lo k(2,3) | hi k(10,11)
        pb0.u[2] = hib ? dw2 : (unsigned)sx0;  // el(4,5): lo k(4,5) | hi k(12,13)
        pb0.u[3] = hib ? dw3 : (unsigned)sx1;  // el(6,7): lo k(6,7) | hi k(14,15)
        pb1.u[0] = hib ? (unsigned)sx6 : dw4;
        pb1.u[1] = hib ? (unsigned)sx7 : dw5;
        pb1.u[2] = hib ? dw6 : (unsigned)sx4;
        pb1.u[3] = hib ? dw7 : (unsigned)sx5;

        // PV: O^T += V^T . P  (dblk d-halves, kc k-chunks of 16)
        {
            int d0 = l32;          // dblk 0
            int d1 = 32 + l32;     // dblk 1
            int sv00 = d0 * 4 + ((2 * 0 + hi) ^ ((d0 >> 1) & 3));
            int sv01 = d0 * 4 + ((2 * 1 + hi) ^ ((d0 >> 1) & 3));
            int sv10 = d1 * 4 + ((2 * 0 + hi) ^ ((d1 >> 1) & 3));
            int sv11 = d1 * 4 + ((2 * 1 + hi) ^ ((d1 >> 1) & 3));
            bf16x8 vf00 = *(const bf16x8*)(&bufp[4096 + sv00 * 16]);
            bf16x8 vf01 = *(const bf16x8*)(&bufp[4096 + sv01 * 16]);
            bf16x8 vf10 = *(const bf16x8*)(&bufp[4096 + sv10 * 16]);
            bf16x8 vf11 = *(const bf16x8*)(&bufp[4096 + sv11 * 16]);
            o0 = MFMA32(vf00, pb0.v, o0);
            o0 = MFMA32(vf01, pb1.v, o0);
            o1 = MFMA32(vf10, pb0.v, o1);
            o1 = MFMA32(vf11, pb1.v, o1);
        }

        mc0 = nm0; mc1 = nm1; mc2 = nm2; mc3 = nm3;
    }
    asm volatile("s_waitcnt vmcnt(0)" ::: "memory");

    la += __shfl_xor(la, 32, 64);  // hi/lo halves cover complementary k-subsets
    int b = bh >> 4, hh = bh & 15;
    float li = 1.f / la;
    size_t row = (size_t)(b * 2048 + qw + l32);
    // O^T C-layout: reg r -> d = (r&3) + 8*(r>>2) + 4*hi (+32 for o1)
#pragma unroll
    for (int rg = 0; rg < 4; rg++) {
        bf16x4 pk0 = {(bf16)(o0[rg * 4 + 0] * li), (bf16)(o0[rg * 4 + 1] * li),
                      (bf16)(o0[rg * 4 + 2] * li), (bf16)(o0[rg * 4 + 3] * li)};
        *(bf16x4*)(&vals[row * 1024 + hh * 64 + rg * 8 + hi * 4]) = pk0;
        bf16x4 pk1 = {(bf16)(o1[rg * 4 + 0] * li), (bf16)(o1[rg * 4 + 1] * li),
                      (bf16)(o1[rg * 4 + 2] * li), (bf16)(o1[rg * 4 + 3] * li)};
        *(bf16x4*)(&vals[row * 1024 + hh * 64 + 32 + rg * 8 + hi * 4]) = pk1;
    }
}

// ---------------- launch ----------------
extern "C" void kernel_launch(void* const* d_in, const int* in_sizes, int n_in,
                              void* d_out, int out_size, void* d_ws, size_t ws_size,
                              hipStream_t stream) {
    const float* x     = (const float*)d_in[0];
    const float* mask  = (const float*)d_in[1];
    const float* w_qkv = (const float*)d_in[2];
    const float* b_qkv = (const float*)d_in[3];
    const float* w_out = (const float*)d_in[4];
    const float* b_out = (const float*)d_in[5];
    float* out = (float*)d_out;

    char* ws = (char*)d_ws;
    size_t off = 0;
    bf16* xb    = (bf16*)(ws + off); off += (size_t)4096 * 1024 * 2;
    bf16* wqkvT = (bf16*)(ws + off); off += (size_t)3072 * 1024 * 2;
    bf16* woutT = (bf16*)(ws + off); off += (size_t)1024 * 1024 * 2;
    bf16* Qa    = (bf16*)(ws + off); off += (size_t)32 * 2048 * 64 * 2;
    bf16* Ka    = (bf16*)(ws + off); off += (size_t)32 * 2048 * 64 * 2;
    bf16* VTa   = (bf16*)(ws + off); off += (size_t)32 * 64 * 2048 * 2;
    bf16* vals  = (bf16*)(ws + off); off += (size_t)4096 * 1024 * 2;

    cast4_kernel<<<4096, 256, 0, stream>>>(x, xb, 4096 * 1024 / 4);
    transpose_cast_kernel<<<dim3(96, 32), dim3(32, 8), 0, stream>>>(w_qkv, wqkvT, 1024, 3072);
    transpose_cast_kernel<<<dim3(32, 32), dim3(32, 8), 0, stream>>>(w_out, woutT, 1024, 1024);
    gemm_qkv_kernel<<<dim3(32, 24), 256, 0, stream>>>(xb, wqkvT, b_qkv, Qa, Ka, VTa);
    attn_kernel<<<512, 256, 0, stream>>>(Qa, Ka, VTa, mask, vals);
    gemm_out_kernel<<<dim3(32, 16), 256, 0, stream>>>(vals, woutT, b_out, out);
}